// Round 7
// baseline (595.206 us; speedup 1.0000x reference)
//
#include <hip/hip_runtime.h>

typedef unsigned short u16;
typedef unsigned int u32;
typedef __attribute__((ext_vector_type(8))) short bf16x8;
typedef __attribute__((ext_vector_type(8))) u16  u16x8;
typedef __attribute__((ext_vector_type(4))) float f32x4;

#define TOK   33048      // B*J*N = 8*17*243
#define NSEQ  243
#define TE    16920576u  // elems per blocked Q/K tensor: 1088*243*64
#define GSTR  15552      // 243*64
#define VTP   256        // padded n-stride of V^T

__device__ __forceinline__ float bf2f(u16 u){
    union { unsigned int i; float f; } v; v.i = ((unsigned int)u) << 16; return v.f;
}
__device__ __forceinline__ u16 f2bf(float f){
    union { float f; unsigned int i; } v; v.f = f;
    unsigned int r = v.i + 0x7fffu + ((v.i >> 16) & 1u);
    return (u16)(r >> 16);
}

__device__ __forceinline__ void gload_lds16(const void* g, void* l){
    __builtin_amdgcn_global_load_lds(
        (const __attribute__((address_space(1))) unsigned int*)g,
        (__attribute__((address_space(3))) unsigned int*)l, 16, 0, 0);
}

// ---------------- x -> token-major bf16 ----------------
__global__ __launch_bounds__(256) void k_cvt_xbf(const float* __restrict__ x, u16* __restrict__ xbf){
    int idx = blockIdx.x*256 + threadIdx.x;
    int t  = idx >> 6;
    int c8 = (idx & 63) << 3;
    unsigned b   = (unsigned)t / 4131u;
    unsigned rem = (unsigned)t % 4131u;
    unsigned j = rem / 243u, n = rem % 243u;
    const float* src = x + ((size_t)(b*243u + n)*17u + j)*512u + c8;
    f32x4 a = *(const f32x4*)src;
    f32x4 c = *(const f32x4*)(src+4);
    u16x8 o;
    #pragma unroll
    for (int e=0;e<4;e++){ o[e]=f2bf(a[e]); o[e+4]=f2bf(c[e]); }
    *(u16x8*)(xbf + (size_t)t*512 + c8) = o;
}

// ---------------- weight conversions ----------------
__global__ __launch_bounds__(256) void k_cvt_wcat(const float* __restrict__ Wqkv,
                                                  const float* __restrict__ Wq,
                                                  const float* __restrict__ Wkv,
                                                  u16* __restrict__ WcatT){
    int idx = blockIdx.x*256 + threadIdx.x;
    int k  = idx / 384;
    int c0 = (idx % 384) * 8;
    const float* src;
    if (c0 < 1536)      src = Wqkv + (size_t)k*1536 + c0;
    else if (c0 < 2048) src = Wq   + (size_t)k*512  + (c0 - 1536);
    else                src = Wkv  + (size_t)k*1024 + (c0 - 2048);
    f32x4 a = *(const f32x4*)src;
    f32x4 b = *(const f32x4*)(src+4);
    #pragma unroll
    for (int e=0;e<4;e++){
        WcatT[(size_t)(c0+e)*512 + k]   = f2bf(a[e]);
        WcatT[(size_t)(c0+4+e)*512 + k] = f2bf(b[e]);
    }
}

__global__ __launch_bounds__(256) void k_cvt_wproj(const float* __restrict__ Wp, u16* __restrict__ WpT){
    int idx = blockIdx.x*256 + threadIdx.x;
    int k  = idx / 64;
    int c0 = (idx % 64) * 8;
    f32x4 a = *(const f32x4*)(Wp + (size_t)k*512 + c0);
    f32x4 b = *(const f32x4*)(Wp + (size_t)k*512 + c0 + 4);
    #pragma unroll
    for (int e=0;e<4;e++){
        WpT[(size_t)(c0+e)*512 + k]   = f2bf(a[e]);
        WpT[(size_t)(c0+4+e)*512 + k] = f2bf(b[e]);
    }
}

// ---------------- input GEMM  M=33048 x N=1536(half) x K=512 ----------------
// writes blocked Q=[g][243][64] @0, K @TE, and V TRANSPOSED VT=[g][64][VTP] @2*TE
__global__ __launch_bounds__(256) void k_gemm_in(
    const u16* __restrict__ xbf, const u16* __restrict__ WcatT,
    const float* __restrict__ b_qkv, const float* __restrict__ b_q,
    const float* __restrict__ b_kv, u16* __restrict__ ws3, int c_off)
{
    __shared__ __align__(16) u16 smem[8192];
    u16* As = smem;
    u16* Bs = smem + 4096;

    // bijective XCD swizzle over 3108 blocks (q=388, r=4)
    const int orig = blockIdx.x;
    const int xcd  = orig & 7;
    const int wg   = (xcd < 4 ? xcd*389 : 4*389 + (xcd-4)*388) + (orig >> 3);
    const int nt = wg % 12, mt = wg / 12;

    const int tid = threadIdx.x;
    const int w = tid >> 6, lane = tid & 63;
    const int wm = w >> 1, wn = w & 1;
    const int lg = lane >> 4, li = lane & 15;

    const int srow = w*16 + (lane >> 2);
    const int scol = (lane & 3) * 8;
    const u16* gA0 = xbf   + (size_t)(mt*128 + srow)*512 + scol;
    const u16* gA1 = gA0 + (size_t)64*512;
    const u16* gB0 = WcatT + (size_t)(c_off + nt*128 + srow)*512 + scol;
    const u16* gB1 = gB0 + (size_t)64*512;
    u16* lA0 = As + w*512;           u16* lA1 = As + 2048 + w*512;
    u16* lB0 = Bs + w*512;           u16* lB1 = Bs + 2048 + w*512;

    f32x4 acc[4][4];
    #pragma unroll
    for (int i=0;i<4;i++)
        #pragma unroll
        for (int jj=0;jj<4;jj++){ acc[i][jj][0]=0.f; acc[i][jj][1]=0.f; acc[i][jj][2]=0.f; acc[i][jj][3]=0.f; }

    for (int k0 = 0; k0 < 512; k0 += 32){
        __syncthreads();
        gload_lds16(gA0 + k0, lA0);
        gload_lds16(gA1 + k0, lA1);
        gload_lds16(gB0 + k0, lB0);
        gload_lds16(gB1 + k0, lB1);
        __syncthreads();
        bf16x8 av[4], bv[4];
        #pragma unroll
        for (int mf=0;mf<4;mf++) av[mf] = *(const bf16x8*)&As[(wm*64 + mf*16 + li)*32 + lg*8];
        #pragma unroll
        for (int nf=0;nf<4;nf++) bv[nf] = *(const bf16x8*)&Bs[(wn*64 + nf*16 + li)*32 + lg*8];
        #pragma unroll
        for (int mf=0;mf<4;mf++)
            #pragma unroll
            for (int nf=0;nf<4;nf++)
                acc[mf][nf] = __builtin_amdgcn_mfma_f32_16x16x32_bf16(av[mf], bv[nf], acc[mf][nf], 0, 0, 0);
    }

    float bias[4];
    #pragma unroll
    for (int nf=0;nf<4;nf++){
        const int c = c_off + nt*128 + wn*64 + nf*16 + li;
        bias[nf] = (c < 1536) ? b_qkv[c] : (c < 2048 ? b_q[c-1536] : b_kv[c-2048]);
    }

    // epilogue: per-wave 16x72 LDS tile -> blocked stores
    u16* L = smem + w*1152;
    const int colbase = nt*128 + wn*64;        // within this half; multiple of 64
    const int slot = colbase >> 9;             // 0=Q,1=K,2=V
    const int hh   = (colbase >> 6) & 7;
    const int rloc = lane & 15;
    const int cchunk = lane >> 4;
    const int dd = (colbase + cchunk*8) & 63;
    u16* tbase = ws3 + (size_t)slot * TE;
    u16* vt    = ws3 + (size_t)2 * TE;

    #pragma unroll
    for (int mf=0;mf<4;mf++){
        __syncthreads();
        #pragma unroll
        for (int nf=0;nf<4;nf++)
            #pragma unroll
            for (int reg=0;reg<4;reg++)
                L[(lg*4+reg)*72 + nf*16 + li] = f2bf(acc[mf][nf][reg] + bias[nf]);
        __syncthreads();
        const int rr_base = mt*128 + wm*64 + mf*16;
        if (slot < 2){
            const int rr = rr_base + rloc;
            if (rr < TOK){
                u16x8 v0 = *(const u16x8*)&L[rloc*72 + cchunk*8];
                u16x8 v1 = *(const u16x8*)&L[rloc*72 + 32 + cchunk*8];
                const unsigned bj = (unsigned)rr / 243u;
                const unsigned n  = (unsigned)rr % 243u;
                u16* dst = tbase + ((size_t)(bj*8u + hh)*243u + n)*64u + dd;
                *(u16x8*)dst      = v0;
                *(u16x8*)(dst+32) = v1;
            }
        } else {
            // V^T: lane owns column d = lane; read 16 u16 down the column
            u16 colv[16];
            #pragma unroll
            for (int r=0;r<16;r++) colv[r] = L[r*72 + lane];
            if (rr_base < TOK){
                const unsigned bj0 = (unsigned)rr_base / 243u;
                const unsigned n0  = (unsigned)rr_base % 243u;
                if (n0 <= 227 && rr_base + 15 < TOK){
                    u16x8 vlo, vhi;
                    #pragma unroll
                    for (int e=0;e<8;e++){ vlo[e]=colv[e]; vhi[e]=colv[e+8]; }
                    u16* dst = vt + ((size_t)(bj0*8u + hh)*64u + lane)*VTP + n0;
                    *(u16x8*)dst     = vlo;
                    *(u16x8*)(dst+8) = vhi;
                } else {
                    for (int r=0;r<16;r++){
                        const int rr = rr_base + r;
                        if (rr < TOK){
                            const unsigned bjr = (unsigned)rr / 243u;
                            const unsigned nr  = (unsigned)rr % 243u;
                            vt[((size_t)(bjr*8u + hh)*64u + lane)*VTP + nr] = colv[r];
                        }
                    }
                }
            }
        }
    }
}

// ---------------- fused attention: NO LDS, no barriers; one (g, q-quarter) per block ----
__constant__ int g_child[17][3] = {
  {1,4,7},{2,-1,-1},{3,-1,-1},{3,-1,-1},{5,-1,-1},{6,-1,-1},{6,-1,-1},{8,-1,-1},
  {9,11,14},{10,-1,-1},{10,-1,-1},{12,-1,-1},{13,-1,-1},{13,-1,-1},{15,-1,-1},
  {16,-1,-1},{16,-1,-1}};
__constant__ float g_cw[17] = {0.33333333f,1,1,1,1,1,1,1,0.33333333f,1,1,1,1,1,1,1,1};

__global__ __launch_bounds__(256, 4) void k_attn(const u16* __restrict__ ws3, u16* __restrict__ attn, int phase)
{
    // XCD-grouping swizzle: the 4 q-quarter blocks of a g land on one XCD
    const int orig = blockIdx.x;               // 4352
    const int xcd  = orig & 7;
    const int l    = orig >> 3;                // 0..543
    const int p    = l & 3;
    const int g    = (l >> 2)*8 + xcd;         // 136 g's per XCD
    const int bj = g >> 3, h = g & 7;
    const int b_ = bj / 17, j_ = bj % 17;

    const int tid = threadIdx.x, lane = tid & 63, w = tid >> 6;
    const int lg = lane >> 4, li = lane & 15;

    const u16* Qb = ws3;
    const u16* Kb = ws3 + (size_t)TE;
    const u16* VT = ws3 + (size_t)2*TE;

    const float scale = (phase == 0) ? 0.125f : 0.125f * g_cw[j_];

    const int qrow0 = p*64 + w*16;
    bf16x8 q0 = {0,0,0,0,0,0,0,0}, q1 = q0;
    const int qr = qrow0 + li;
    if (qr < NSEQ){
        const u16* qp = Qb + (size_t)g*GSTR + (size_t)qr*64;
        q0 = *(const bf16x8*)(qp + lg*8);
        q1 = *(const bf16x8*)(qp + 32 + lg*8);
    }

    // S^T: lane li owns q-row li; fused QK -> mask -> exp (drop-max) -> sum -> pack
    u32 ulo[16], uhi[16];
    float s0acc=0.f, s1acc=0.f, s2acc=0.f, s3acc=0.f;
    #pragma unroll
    for (int nt2=0; nt2<16; nt2++){
        f32x4 s; s[0]=0.f; s[1]=0.f; s[2]=0.f; s[3]=0.f;
        if (phase == 0){
            const u16* kp = Kb + (size_t)g*GSTR + (size_t)(nt2*16+li)*64;
            const bf16x8 kb0 = *(const bf16x8*)(kp + lg*8);
            const bf16x8 kb1 = *(const bf16x8*)(kp + 32 + lg*8);
            s = __builtin_amdgcn_mfma_f32_16x16x32_bf16(kb0, q0, s, 0,0,0);
            s = __builtin_amdgcn_mfma_f32_16x16x32_bf16(kb1, q1, s, 0,0,0);
        } else {
            #pragma unroll
            for (int ci=0; ci<3; ci++){
                const int cj = g_child[j_][ci];
                if (cj >= 0){
                    const u16* kp = Kb + (size_t)((b_*17+cj)*8 + h)*GSTR + (size_t)(nt2*16+li)*64;
                    const bf16x8 kb0 = *(const bf16x8*)(kp + lg*8);
                    const bf16x8 kb1 = *(const bf16x8*)(kp + 32 + lg*8);
                    s = __builtin_amdgcn_mfma_f32_16x16x32_bf16(kb0, q0, s, 0,0,0);
                    s = __builtin_amdgcn_mfma_f32_16x16x32_bf16(kb1, q1, s, 0,0,0);
                }
            }
        }
        if (nt2 == 15){
            s[3] = -1e30f;
            if (lg){ s[0] = -1e30f; s[1] = -1e30f; s[2] = -1e30f; }
        }
        const float p0 = __expf(scale*s[0]);
        const float p1 = __expf(scale*s[1]);
        const float p2 = __expf(scale*s[2]);
        const float p3 = __expf(scale*s[3]);
        s0acc += p0; s1acc += p1; s2acc += p2; s3acc += p3;
        ulo[nt2] = (u32)f2bf(p0) | ((u32)f2bf(p1) << 16);
        uhi[nt2] = (u32)f2bf(p2) | ((u32)f2bf(p3) << 16);
    }
    float sum = (s0acc + s1acc) + (s2acc + s3acc);
    sum += __shfl_xor(sum,16);
    sum += __shfl_xor(sum,32);
    const float inv = 1.f/sum;

    // redistribute to PV A-fragments: pa[kt] elem e = P[q=li][k=kt*32+lg*8+e]
    const int laneA = li + 32*(lg & 1);
    const int laneB = laneA + 16;
    const bool sel = (lg >> 1) != 0;
    bf16x8 pa[8];
    #pragma unroll
    for (int kt=0; kt<8; kt++){
        u32 a0 = __shfl((int)ulo[2*kt],   laneA), a1 = __shfl((int)ulo[2*kt+1], laneA);
        u32 b0 = __shfl((int)uhi[2*kt],   laneA), b1 = __shfl((int)uhi[2*kt+1], laneA);
        u32 c0 = __shfl((int)ulo[2*kt],   laneB), c1 = __shfl((int)ulo[2*kt+1], laneB);
        u32 d0 = __shfl((int)uhi[2*kt],   laneB), d1 = __shfl((int)uhi[2*kt+1], laneB);
        union { u32 u[4]; bf16x8 v; } pk;
        pk.u[0] = sel ? a1 : a0;
        pk.u[1] = sel ? b1 : b0;
        pk.u[2] = sel ? c1 : c0;
        pk.u[3] = sel ? d1 : d0;
        pa[kt] = pk.v;
    }
    const float cwo = (phase == 0) ? 1.f : g_cw[j_];
    float invr[4];
    #pragma unroll
    for (int r=0;r<4;r++) invr[r] = __shfl(inv, lg*4+r) * cwo;

    // O = P V from global V^T (phase 1: O = sum over children)
    #pragma unroll
    for (int dn=0;dn<4;dn++){
        f32x4 o; o[0]=0.f; o[1]=0.f; o[2]=0.f; o[3]=0.f;
        if (phase == 0){
            const u16* vbase = VT + ((size_t)g*64 + dn*16 + li)*VTP;
            #pragma unroll
            for (int kt=0;kt<8;kt++){
                const bf16x8 vb = *(const bf16x8*)(vbase + kt*32 + lg*8);
                o = __builtin_amdgcn_mfma_f32_16x16x32_bf16(pa[kt], vb, o, 0,0,0);
            }
        } else {
            #pragma unroll
            for (int ci=0; ci<3; ci++){
                const int cj = g_child[j_][ci];
                if (cj >= 0){
                    const u16* vbase = VT + ((size_t)((b_*17+cj)*8 + h)*64 + dn*16 + li)*VTP;
                    #pragma unroll
                    for (int kt=0;kt<8;kt++){
                        const bf16x8 vb = *(const bf16x8*)(vbase + kt*32 + lg*8);
                        o = __builtin_amdgcn_mfma_f32_16x16x32_bf16(pa[kt], vb, o, 0,0,0);
                    }
                }
            }
        }
        #pragma unroll
        for (int r=0;r<4;r++){
            const int qrow = qrow0 + lg*4 + r;
            if (qrow < NSEQ){
                const size_t off = ((size_t)bj*243 + qrow)*512 + h*64 + dn*16 + li;
                float val = o[r] * invr[r];
                if (phase == 1) val += bf2f(attn[off]);
                attn[off] = f2bf(val);
            }
        }
    }
}

// ---------------- projection GEMM  M=33048 x N=512 x K=512 -> fp32 fuse ----------------
__global__ __launch_bounds__(256) void k_gemm_proj(
    const u16* __restrict__ attnb, const u16* __restrict__ WprojT,
    const float* __restrict__ b_proj, float* __restrict__ fuse)
{
    __shared__ __align__(16) u16 smem[8192];
    u16* As = smem;
    u16* Bs = smem + 4096;

    const int orig = blockIdx.x;
    const int xcd  = orig & 7;
    const int wg   = (xcd < 4 ? xcd*130 : 4*130 + (xcd-4)*129) + (orig >> 3);
    const int nt = wg & 3, mt = wg >> 2;

    const int tid = threadIdx.x;
    const int w = tid >> 6, lane = tid & 63;
    const int wm = w >> 1, wn = w & 1;
    const int lg = lane >> 4, li = lane & 15;

    const int srow = w*16 + (lane >> 2);
    const int scol = (lane & 3) * 8;
    const u16* gA0 = attnb  + (size_t)(mt*128 + srow)*512 + scol;
    const u16* gA1 = gA0 + (size_t)64*512;
    const u16* gB0 = WprojT + (size_t)(nt*128 + srow)*512 + scol;
    const u16* gB1 = gB0 + (size_t)64*512;
    u16* lA0 = As + w*512;           u16* lA1 = As + 2048 + w*512;
    u16* lB0 = Bs + w*512;           u16* lB1 = Bs + 2048 + w*512;

    f32x4 acc[4][4];
    #pragma unroll
    for (int i=0;i<4;i++)
        #pragma unroll
        for (int jj=0;jj<4;jj++){ acc[i][jj][0]=0.f; acc[i][jj][1]=0.f; acc[i][jj][2]=0.f; acc[i][jj][3]=0.f; }

    for (int k0 = 0; k0 < 512; k0 += 32){
        __syncthreads();
        gload_lds16(gA0 + k0, lA0);
        gload_lds16(gA1 + k0, lA1);
        gload_lds16(gB0 + k0, lB0);
        gload_lds16(gB1 + k0, lB1);
        __syncthreads();
        bf16x8 av[4], bv[4];
        #pragma unroll
        for (int mf=0;mf<4;mf++) av[mf] = *(const bf16x8*)&As[(wm*64 + mf*16 + li)*32 + lg*8];
        #pragma unroll
        for (int nf=0;nf<4;nf++) bv[nf] = *(const bf16x8*)&Bs[(wn*64 + nf*16 + li)*32 + lg*8];
        #pragma unroll
        for (int mf=0;mf<4;mf++)
            #pragma unroll
            for (int nf=0;nf<4;nf++)
                acc[mf][nf] = __builtin_amdgcn_mfma_f32_16x16x32_bf16(av[mf], bv[nf], acc[mf][nf], 0, 0, 0);
    }

    #pragma unroll
    for (int mf=0;mf<4;mf++)
        #pragma unroll
        for (int reg=0;reg<4;reg++){
            const int rr = mt*128 + wm*64 + mf*16 + lg*4 + reg;
            if (rr < TOK){
                #pragma unroll
                for (int nf=0;nf<4;nf++){
                    const int c = nt*128 + wn*64 + nf*16 + li;
                    fuse[(size_t)rr*512 + c] = acc[mf][nf][reg] + b_proj[c];
                }
            }
        }
}

// ---------------- residual + LayerNorm (with (b,j,n)->(b,n,j) permute) ----------------
__global__ __launch_bounds__(256) void k_ln(
    const float* __restrict__ x, const float* __restrict__ fuse, float* __restrict__ out)
{
    const int w = threadIdx.x >> 6, lane = threadIdx.x & 63;
    const int o = blockIdx.x*4 + w;
    const unsigned b_  = (unsigned)o / 4131u;
    const unsigned rem = (unsigned)o % 4131u;
    const unsigned n = rem / 17u, j = rem % 17u;
    const unsigned t = (b_*17u + j)*243u + n;
    const float* fr = fuse + (size_t)t*512 + lane*8;
    const float* xr = x    + (size_t)o*512 + lane*8;
    f32x4 f0 = *(const f32x4*)fr, f1 = *(const f32x4*)(fr+4);
    f32x4 x0 = *(const f32x4*)xr, x1 = *(const f32x4*)(xr+4);
    float y[8];
    #pragma unroll
    for (int e=0;e<4;e++){ y[e] = x0[e]+f0[e]; y[e+4] = x1[e]+f1[e]; }
    float s1=0.f, s2=0.f;
    #pragma unroll
    for (int e=0;e<8;e++){ s1 += y[e]; s2 += y[e]*y[e]; }
    #pragma unroll
    for (int m=1;m<64;m<<=1){ s1 += __shfl_xor(s1,m); s2 += __shfl_xor(s2,m); }
    const float mu  = s1 * (1.f/512.f);
    const float var = s2 * (1.f/512.f) - mu*mu;
    const float rstd = rsqrtf(var + 1e-5f);
    float* orow = out + (size_t)o*512 + lane*8;
    f32x4 o0, o1;
    #pragma unroll
    for (int e=0;e<4;e++){ o0[e] = (y[e]-mu)*rstd; o1[e] = (y[e+4]-mu)*rstd; }
    *(f32x4*)orow = o0; *(f32x4*)(orow+4) = o1;
}

extern "C" void kernel_launch(void* const* d_in, const int* in_sizes, int n_in,
                              void* d_out, int out_size, void* d_ws, size_t ws_size,
                              hipStream_t stream)
{
    const float* x      = (const float*)d_in[0];
    const float* W_qkv  = (const float*)d_in[1];
    const float* b_qkv  = (const float*)d_in[2];
    const float* W_q    = (const float*)d_in[3];
    const float* b_q    = (const float*)d_in[4];
    const float* W_kv   = (const float*)d_in[5];
    const float* b_kv   = (const float*)d_in[6];
    const float* W_proj = (const float*)d_in[7];
    const float* b_proj = (const float*)d_in[8];

    // workspace layout (peak ~175 MB):
    //   [0, 33972224)              xbf  bf16 [33048+pad][512]
    //   [33972224, 137306112)      ws3: Q [1088][243][64], K same, VT [1088][64][256]
    //   [137306112, 171278336)     attn bf16 [33048+pad][512]
    //   [171278336, 174424064)     WcatT bf16 [3072][512]
    //   [174424064, 174948352)     WprojT bf16 [512][512]
    //   fuse fp32 aliases ws3 (dead after attn phase 1)
    char* ws = (char*)d_ws;
    u16*   xbf    = (u16*)(ws);
    u16*   ws3    = (u16*)(ws + 33972224u);
    u16*   attn   = (u16*)(ws + 137306112u);
    u16*   WcatT  = (u16*)(ws + 171278336u);
    u16*   WprojT = (u16*)(ws + 174424064u);
    float* fuse   = (float*)(ws + 33972224u);
    float* out    = (float*)d_out;

    k_cvt_xbf  <<<8262, 256, 0, stream>>>(x, xbf);
    k_cvt_wcat <<<768,  256, 0, stream>>>(W_qkv, W_q, W_kv, WcatT);
    k_cvt_wproj<<<128,  256, 0, stream>>>(W_proj, WprojT);

    k_gemm_in<<<3108, 256, 0, stream>>>(xbf, WcatT, b_qkv, b_q, b_kv, ws3, 0);
    k_attn<<<4352, 256, 0, stream>>>(ws3, attn, 0);

    k_gemm_in<<<3108, 256, 0, stream>>>(xbf, WcatT, b_qkv, b_q, b_kv, ws3, 1536);
    k_attn<<<4352, 256, 0, stream>>>(ws3, attn, 1);

    k_gemm_proj<<<1036, 256, 0, stream>>>(attn, WprojT, b_proj, fuse);

    k_ln<<<8262, 256, 0, stream>>>(x, fuse, out);
}

// Round 8
// 476.244 us; speedup vs baseline: 1.2498x; 1.2498x over previous
//
#include <hip/hip_runtime.h>

typedef unsigned short u16;
typedef unsigned int u32;
typedef __attribute__((ext_vector_type(8))) short bf16x8;
typedef __attribute__((ext_vector_type(8))) u16  u16x8;
typedef __attribute__((ext_vector_type(4))) float f32x4;

#define TOK   33048      // B*J*N = 8*17*243
#define NSEQ  243
#define TE    16920576u  // elems per blocked Q/K tensor: 1088*243*64
#define GSTR  15552      // 243*64
#define VTP   256        // padded n-stride of V^T

__device__ __forceinline__ float bf2f(u16 u){
    union { unsigned int i; float f; } v; v.i = ((unsigned int)u) << 16; return v.f;
}
__device__ __forceinline__ u16 f2bf(float f){
    union { float f; unsigned int i; } v; v.f = f;
    unsigned int r = v.i + 0x7fffu + ((v.i >> 16) & 1u);
    return (u16)(r >> 16);
}

__device__ __forceinline__ void gload_lds16(const void* g, void* l){
    __builtin_amdgcn_global_load_lds(
        (const __attribute__((address_space(1))) unsigned int*)g,
        (__attribute__((address_space(3))) unsigned int*)l, 16, 0, 0);
}

// ---------------- x -> token-major bf16 ----------------
__global__ __launch_bounds__(256) void k_cvt_xbf(const float* __restrict__ x, u16* __restrict__ xbf){
    int idx = blockIdx.x*256 + threadIdx.x;
    int t  = idx >> 6;
    int c8 = (idx & 63) << 3;
    unsigned b   = (unsigned)t / 4131u;
    unsigned rem = (unsigned)t % 4131u;
    unsigned j = rem / 243u, n = rem % 243u;
    const float* src = x + ((size_t)(b*243u + n)*17u + j)*512u + c8;
    f32x4 a = *(const f32x4*)src;
    f32x4 c = *(const f32x4*)(src+4);
    u16x8 o;
    #pragma unroll
    for (int e=0;e<4;e++){ o[e]=f2bf(a[e]); o[e+4]=f2bf(c[e]); }
    *(u16x8*)(xbf + (size_t)t*512 + c8) = o;
}

// ---------------- weight conversions ----------------
__global__ __launch_bounds__(256) void k_cvt_wcat(const float* __restrict__ Wqkv,
                                                  const float* __restrict__ Wq,
                                                  const float* __restrict__ Wkv,
                                                  u16* __restrict__ WcatT){
    int idx = blockIdx.x*256 + threadIdx.x;
    int k  = idx / 384;
    int c0 = (idx % 384) * 8;
    const float* src;
    if (c0 < 1536)      src = Wqkv + (size_t)k*1536 + c0;
    else if (c0 < 2048) src = Wq   + (size_t)k*512  + (c0 - 1536);
    else                src = Wkv  + (size_t)k*1024 + (c0 - 2048);
    f32x4 a = *(const f32x4*)src;
    f32x4 b = *(const f32x4*)(src+4);
    #pragma unroll
    for (int e=0;e<4;e++){
        WcatT[(size_t)(c0+e)*512 + k]   = f2bf(a[e]);
        WcatT[(size_t)(c0+4+e)*512 + k] = f2bf(b[e]);
    }
}

__global__ __launch_bounds__(256) void k_cvt_wproj(const float* __restrict__ Wp, u16* __restrict__ WpT){
    int idx = blockIdx.x*256 + threadIdx.x;
    int k  = idx / 64;
    int c0 = (idx % 64) * 8;
    f32x4 a = *(const f32x4*)(Wp + (size_t)k*512 + c0);
    f32x4 b = *(const f32x4*)(Wp + (size_t)k*512 + c0 + 4);
    #pragma unroll
    for (int e=0;e<4;e++){
        WpT[(size_t)(c0+e)*512 + k]   = f2bf(a[e]);
        WpT[(size_t)(c0+4+e)*512 + k] = f2bf(b[e]);
    }
}

// ---------------- input GEMM  M=33048 x N=1536(half) x K=512 ----------------
// writes blocked Q=[g][243][64] @0, K @TE, and V TRANSPOSED VT=[g][64][VTP] @2*TE
__global__ __launch_bounds__(256) void k_gemm_in(
    const u16* __restrict__ xbf, const u16* __restrict__ WcatT,
    const float* __restrict__ b_qkv, const float* __restrict__ b_q,
    const float* __restrict__ b_kv, u16* __restrict__ ws3, int c_off)
{
    __shared__ __align__(16) u16 smem[8192];
    u16* As = smem;
    u16* Bs = smem + 4096;

    // bijective XCD swizzle over 3108 blocks (q=388, r=4)
    const int orig = blockIdx.x;
    const int xcd  = orig & 7;
    const int wg   = (xcd < 4 ? xcd*389 : 4*389 + (xcd-4)*388) + (orig >> 3);
    const int nt = wg % 12, mt = wg / 12;

    const int tid = threadIdx.x;
    const int w = tid >> 6, lane = tid & 63;
    const int wm = w >> 1, wn = w & 1;
    const int lg = lane >> 4, li = lane & 15;

    const int srow = w*16 + (lane >> 2);
    const int scol = (lane & 3) * 8;
    const u16* gA0 = xbf   + (size_t)(mt*128 + srow)*512 + scol;
    const u16* gA1 = gA0 + (size_t)64*512;
    const u16* gB0 = WcatT + (size_t)(c_off + nt*128 + srow)*512 + scol;
    const u16* gB1 = gB0 + (size_t)64*512;
    u16* lA0 = As + w*512;           u16* lA1 = As + 2048 + w*512;
    u16* lB0 = Bs + w*512;           u16* lB1 = Bs + 2048 + w*512;

    f32x4 acc[4][4];
    #pragma unroll
    for (int i=0;i<4;i++)
        #pragma unroll
        for (int jj=0;jj<4;jj++){ acc[i][jj][0]=0.f; acc[i][jj][1]=0.f; acc[i][jj][2]=0.f; acc[i][jj][3]=0.f; }

    for (int k0 = 0; k0 < 512; k0 += 32){
        __syncthreads();
        gload_lds16(gA0 + k0, lA0);
        gload_lds16(gA1 + k0, lA1);
        gload_lds16(gB0 + k0, lB0);
        gload_lds16(gB1 + k0, lB1);
        __syncthreads();
        bf16x8 av[4], bv[4];
        #pragma unroll
        for (int mf=0;mf<4;mf++) av[mf] = *(const bf16x8*)&As[(wm*64 + mf*16 + li)*32 + lg*8];
        #pragma unroll
        for (int nf=0;nf<4;nf++) bv[nf] = *(const bf16x8*)&Bs[(wn*64 + nf*16 + li)*32 + lg*8];
        #pragma unroll
        for (int mf=0;mf<4;mf++)
            #pragma unroll
            for (int nf=0;nf<4;nf++)
                acc[mf][nf] = __builtin_amdgcn_mfma_f32_16x16x32_bf16(av[mf], bv[nf], acc[mf][nf], 0, 0, 0);
    }

    float bias[4];
    #pragma unroll
    for (int nf=0;nf<4;nf++){
        const int c = c_off + nt*128 + wn*64 + nf*16 + li;
        bias[nf] = (c < 1536) ? b_qkv[c] : (c < 2048 ? b_q[c-1536] : b_kv[c-2048]);
    }

    // epilogue: per-wave 16x72 LDS tile -> blocked stores
    u16* L = smem + w*1152;
    const int colbase = nt*128 + wn*64;        // within this half; multiple of 64
    const int slot = colbase >> 9;             // 0=Q,1=K,2=V
    const int hh   = (colbase >> 6) & 7;
    const int rloc = lane & 15;
    const int cchunk = lane >> 4;
    const int dd = (colbase + cchunk*8) & 63;
    u16* tbase = ws3 + (size_t)slot * TE;
    u16* vt    = ws3 + (size_t)2 * TE;

    #pragma unroll
    for (int mf=0;mf<4;mf++){
        __syncthreads();
        #pragma unroll
        for (int nf=0;nf<4;nf++)
            #pragma unroll
            for (int reg=0;reg<4;reg++)
                L[(lg*4+reg)*72 + nf*16 + li] = f2bf(acc[mf][nf][reg] + bias[nf]);
        __syncthreads();
        const int rr_base = mt*128 + wm*64 + mf*16;
        if (slot < 2){
            const int rr = rr_base + rloc;
            if (rr < TOK){
                u16x8 v0 = *(const u16x8*)&L[rloc*72 + cchunk*8];
                u16x8 v1 = *(const u16x8*)&L[rloc*72 + 32 + cchunk*8];
                const unsigned bj = (unsigned)rr / 243u;
                const unsigned n  = (unsigned)rr % 243u;
                u16* dst = tbase + ((size_t)(bj*8u + hh)*243u + n)*64u + dd;
                *(u16x8*)dst      = v0;
                *(u16x8*)(dst+32) = v1;
            }
        } else {
            // V^T: lane owns column d = lane; read 16 u16 down the column
            u16 colv[16];
            #pragma unroll
            for (int r=0;r<16;r++) colv[r] = L[r*72 + lane];
            if (rr_base < TOK){
                const unsigned bj0 = (unsigned)rr_base / 243u;
                const unsigned n0  = (unsigned)rr_base % 243u;
                if (n0 <= 227 && rr_base + 15 < TOK){
                    u16x8 vlo, vhi;
                    #pragma unroll
                    for (int e=0;e<8;e++){ vlo[e]=colv[e]; vhi[e]=colv[e+8]; }
                    u16* dst = vt + ((size_t)(bj0*8u + hh)*64u + lane)*VTP + n0;
                    *(u16x8*)dst     = vlo;
                    *(u16x8*)(dst+8) = vhi;
                } else {
                    for (int r=0;r<16;r++){
                        const int rr = rr_base + r;
                        if (rr < TOK){
                            const unsigned bjr = (unsigned)rr / 243u;
                            const unsigned nr  = (unsigned)rr % 243u;
                            vt[((size_t)(bjr*8u + hh)*64u + lane)*VTP + nr] = colv[r];
                        }
                    }
                }
            }
        }
    }
}

// ---------------- fused attention: no LDS/barriers; 2 q-tiles per wave ----------------
// grid 2176 = 1088 g x 2 halves; block covers 128 q-rows (4 waves x 2 tiles of 16)
__constant__ int g_child[17][3] = {
  {1,4,7},{2,-1,-1},{3,-1,-1},{3,-1,-1},{5,-1,-1},{6,-1,-1},{6,-1,-1},{8,-1,-1},
  {9,11,14},{10,-1,-1},{10,-1,-1},{12,-1,-1},{13,-1,-1},{13,-1,-1},{15,-1,-1},
  {16,-1,-1},{16,-1,-1}};
__constant__ float g_cw[17] = {0.33333333f,1,1,1,1,1,1,1,0.33333333f,1,1,1,1,1,1,1,1};

__global__ __launch_bounds__(256, 2) void k_attn(const u16* __restrict__ ws3, u16* __restrict__ attn, int phase)
{
    // XCD-grouping swizzle: both halves of a g land on one XCD
    const int orig = blockIdx.x;               // 2176
    const int xcd  = orig & 7;
    const int l    = orig >> 3;                // 0..271
    const int p2   = l & 1;
    const int g    = (l >> 1)*8 + xcd;
    const int bj = g >> 3, h = g & 7;
    const int b_ = bj / 17, j_ = bj % 17;

    const int tid = threadIdx.x, lane = tid & 63, w = tid >> 6;
    const int lg = lane >> 4, li = lane & 15;

    const u16* Qb = ws3;
    const u16* Kb = ws3 + (size_t)TE;
    const u16* VT = ws3 + (size_t)2*TE;

    const float scale = (phase == 0) ? 0.125f : 0.125f * g_cw[j_];

    const int qrowA = p2*128 + w*16;
    const int qrowB = qrowA + 64;

    bf16x8 qA0 = {0,0,0,0,0,0,0,0}, qA1 = qA0, qB0 = qA0, qB1 = qA0;
    {
        const int qrA = qrowA + li;
        const u16* qp = Qb + (size_t)g*GSTR + (size_t)qrA*64;
        qA0 = *(const bf16x8*)(qp + lg*8);
        qA1 = *(const bf16x8*)(qp + 32 + lg*8);
        const int qrB = qrowB + li;
        if (qrB < NSEQ){
            const u16* qp2 = Qb + (size_t)g*GSTR + (size_t)qrB*64;
            qB0 = *(const bf16x8*)(qp2 + lg*8);
            qB1 = *(const bf16x8*)(qp2 + 32 + lg*8);
        }
    }

    // child K/V base offsets (wave-uniform)
    size_t kgb[3]; int nch = 0;
    if (phase == 0){
        kgb[0] = (size_t)g*GSTR; nch = 1;
    } else {
        #pragma unroll
        for (int ci=0; ci<3; ci++){
            const int cj = g_child[j_][ci];
            if (cj >= 0) kgb[nch++] = (size_t)((b_*17+cj)*8 + h)*GSTR;
        }
    }

    // S^T: lane li owns q-row li of each tile; fused QK -> mask -> exp -> sum -> pack
    u32 uloA[16], uhiA[16], uloB[16], uhiB[16];
    float sumA = 0.f, sumB = 0.f;
    #pragma unroll
    for (int nt2=0; nt2<16; nt2++){
        f32x4 sA; sA[0]=0.f; sA[1]=0.f; sA[2]=0.f; sA[3]=0.f;
        f32x4 sB = sA;
        const size_t krow = (size_t)(nt2*16+li)*64;
        if (nch == 1){
            const u16* kp = Kb + kgb[0] + krow;
            const bf16x8 kb0 = *(const bf16x8*)(kp + lg*8);
            const bf16x8 kb1 = *(const bf16x8*)(kp + 32 + lg*8);
            sA = __builtin_amdgcn_mfma_f32_16x16x32_bf16(kb0, qA0, sA, 0,0,0);
            sA = __builtin_amdgcn_mfma_f32_16x16x32_bf16(kb1, qA1, sA, 0,0,0);
            sB = __builtin_amdgcn_mfma_f32_16x16x32_bf16(kb0, qB0, sB, 0,0,0);
            sB = __builtin_amdgcn_mfma_f32_16x16x32_bf16(kb1, qB1, sB, 0,0,0);
        } else {
            #pragma unroll
            for (int c=0;c<3;c++){
                const u16* kp = Kb + kgb[c] + krow;
                const bf16x8 kb0 = *(const bf16x8*)(kp + lg*8);
                const bf16x8 kb1 = *(const bf16x8*)(kp + 32 + lg*8);
                sA = __builtin_amdgcn_mfma_f32_16x16x32_bf16(kb0, qA0, sA, 0,0,0);
                sA = __builtin_amdgcn_mfma_f32_16x16x32_bf16(kb1, qA1, sA, 0,0,0);
                sB = __builtin_amdgcn_mfma_f32_16x16x32_bf16(kb0, qB0, sB, 0,0,0);
                sB = __builtin_amdgcn_mfma_f32_16x16x32_bf16(kb1, qB1, sB, 0,0,0);
            }
        }
        if (nt2 == 15){
            sA[3] = -1e30f; sB[3] = -1e30f;
            if (lg){ sA[0]=-1e30f; sA[1]=-1e30f; sA[2]=-1e30f;
                     sB[0]=-1e30f; sB[1]=-1e30f; sB[2]=-1e30f; }
        }
        const float a0 = __expf(scale*sA[0]);
        const float a1 = __expf(scale*sA[1]);
        const float a2 = __expf(scale*sA[2]);
        const float a3 = __expf(scale*sA[3]);
        sumA += (a0+a1)+(a2+a3);
        uloA[nt2] = (u32)f2bf(a0) | ((u32)f2bf(a1) << 16);
        uhiA[nt2] = (u32)f2bf(a2) | ((u32)f2bf(a3) << 16);
        const float b0 = __expf(scale*sB[0]);
        const float b1 = __expf(scale*sB[1]);
        const float b2 = __expf(scale*sB[2]);
        const float b3 = __expf(scale*sB[3]);
        sumB += (b0+b1)+(b2+b3);
        uloB[nt2] = (u32)f2bf(b0) | ((u32)f2bf(b1) << 16);
        uhiB[nt2] = (u32)f2bf(b2) | ((u32)f2bf(b3) << 16);
    }
    sumA += __shfl_xor(sumA,16); sumA += __shfl_xor(sumA,32);
    sumB += __shfl_xor(sumB,16); sumB += __shfl_xor(sumB,32);
    const float invA = 1.f/sumA;
    const float invB = 1.f/sumB;

    // redistribute to PV A-fragments: pa[kt] elem e = P[q=li][k=kt*32+lg*8+e]
    const int laneA = li + 32*(lg & 1);
    const int laneB = laneA + 16;
    const bool sel = (lg >> 1) != 0;
    bf16x8 paA[8], paB[8];
    #pragma unroll
    for (int kt=0; kt<8; kt++){
        u32 a0 = __shfl((int)uloA[2*kt],   laneA), a1 = __shfl((int)uloA[2*kt+1], laneA);
        u32 b0 = __shfl((int)uhiA[2*kt],   laneA), b1 = __shfl((int)uhiA[2*kt+1], laneA);
        u32 c0 = __shfl((int)uloA[2*kt],   laneB), c1 = __shfl((int)uloA[2*kt+1], laneB);
        u32 d0 = __shfl((int)uhiA[2*kt],   laneB), d1 = __shfl((int)uhiA[2*kt+1], laneB);
        union { u32 u[4]; bf16x8 v; } pk;
        pk.u[0] = sel ? a1 : a0;
        pk.u[1] = sel ? b1 : b0;
        pk.u[2] = sel ? c1 : c0;
        pk.u[3] = sel ? d1 : d0;
        paA[kt] = pk.v;
    }
    #pragma unroll
    for (int kt=0; kt<8; kt++){
        u32 a0 = __shfl((int)uloB[2*kt],   laneA), a1 = __shfl((int)uloB[2*kt+1], laneA);
        u32 b0 = __shfl((int)uhiB[2*kt],   laneA), b1 = __shfl((int)uhiB[2*kt+1], laneA);
        u32 c0 = __shfl((int)uloB[2*kt],   laneB), c1 = __shfl((int)uloB[2*kt+1], laneB);
        u32 d0 = __shfl((int)uhiB[2*kt],   laneB), d1 = __shfl((int)uhiB[2*kt+1], laneB);
        union { u32 u[4]; bf16x8 v; } pk;
        pk.u[0] = sel ? a1 : a0;
        pk.u[1] = sel ? b1 : b0;
        pk.u[2] = sel ? c1 : c0;
        pk.u[3] = sel ? d1 : d0;
        paB[kt] = pk.v;
    }
    const float cwo = (phase == 0) ? 1.f : g_cw[j_];
    float invrA[4], invrB[4];
    #pragma unroll
    for (int r=0;r<4;r++){
        invrA[r] = __shfl(invA, lg*4+r) * cwo;
        invrB[r] = __shfl(invB, lg*4+r) * cwo;
    }

    // O = P V from global V^T (phase 1: O = sum over children); vb shared by both tiles
    #pragma unroll
    for (int dn=0;dn<4;dn++){
        f32x4 oA; oA[0]=0.f; oA[1]=0.f; oA[2]=0.f; oA[3]=0.f;
        f32x4 oB = oA;
        const size_t vrow = ((size_t)(dn*16 + li))*VTP;
        if (nch == 1){
            const u16* vbase = VT + kgb[0]/GSTR*((size_t)64*VTP) + vrow;
            bf16x8 vb[8];
            #pragma unroll
            for (int kt=0;kt<8;kt++) vb[kt] = *(const bf16x8*)(vbase + kt*32 + lg*8);
            #pragma unroll
            for (int kt=0;kt<8;kt++){
                oA = __builtin_amdgcn_mfma_f32_16x16x32_bf16(paA[kt], vb[kt], oA, 0,0,0);
                oB = __builtin_amdgcn_mfma_f32_16x16x32_bf16(paB[kt], vb[kt], oB, 0,0,0);
            }
        } else {
            #pragma unroll
            for (int c=0;c<3;c++){
                const u16* vbase = VT + kgb[c]/GSTR*((size_t)64*VTP) + vrow;
                bf16x8 vb[8];
                #pragma unroll
                for (int kt=0;kt<8;kt++) vb[kt] = *(const bf16x8*)(vbase + kt*32 + lg*8);
                #pragma unroll
                for (int kt=0;kt<8;kt++){
                    oA = __builtin_amdgcn_mfma_f32_16x16x32_bf16(paA[kt], vb[kt], oA, 0,0,0);
                    oB = __builtin_amdgcn_mfma_f32_16x16x32_bf16(paB[kt], vb[kt], oB, 0,0,0);
                }
            }
        }
        #pragma unroll
        for (int r=0;r<4;r++){
            const int qrow = qrowA + lg*4 + r;
            const size_t off = ((size_t)bj*243 + qrow)*512 + h*64 + dn*16 + li;
            float val = oA[r] * invrA[r];
            if (phase == 1) val += bf2f(attn[off]);
            attn[off] = f2bf(val);
        }
        #pragma unroll
        for (int r=0;r<4;r++){
            const int qrow = qrowB + lg*4 + r;
            if (qrow < NSEQ){
                const size_t off = ((size_t)bj*243 + qrow)*512 + h*64 + dn*16 + li;
                float val = oB[r] * invrB[r];
                if (phase == 1) val += bf2f(attn[off]);
                attn[off] = f2bf(val);
            }
        }
    }
}

// ---------------- projection GEMM  M=33048 x N=512 x K=512 -> fp32 fuse ----------------
__global__ __launch_bounds__(256) void k_gemm_proj(
    const u16* __restrict__ attnb, const u16* __restrict__ WprojT,
    const float* __restrict__ b_proj, float* __restrict__ fuse)
{
    __shared__ __align__(16) u16 smem[8192];
    u16* As = smem;
    u16* Bs = smem + 4096;

    const int orig = blockIdx.x;
    const int xcd  = orig & 7;
    const int wg   = (xcd < 4 ? xcd*130 : 4*130 + (xcd-4)*129) + (orig >> 3);
    const int nt = wg & 3, mt = wg >> 2;

    const int tid = threadIdx.x;
    const int w = tid >> 6, lane = tid & 63;
    const int wm = w >> 1, wn = w & 1;
    const int lg = lane >> 4, li = lane & 15;

    const int srow = w*16 + (lane >> 2);
    const int scol = (lane & 3) * 8;
    const u16* gA0 = attnb  + (size_t)(mt*128 + srow)*512 + scol;
    const u16* gA1 = gA0 + (size_t)64*512;
    const u16* gB0 = WprojT + (size_t)(nt*128 + srow)*512 + scol;
    const u16* gB1 = gB0 + (size_t)64*512;
    u16* lA0 = As + w*512;           u16* lA1 = As + 2048 + w*512;
    u16* lB0 = Bs + w*512;           u16* lB1 = Bs + 2048 + w*512;

    f32x4 acc[4][4];
    #pragma unroll
    for (int i=0;i<4;i++)
        #pragma unroll
        for (int jj=0;jj<4;jj++){ acc[i][jj][0]=0.f; acc[i][jj][1]=0.f; acc[i][jj][2]=0.f; acc[i][jj][3]=0.f; }

    for (int k0 = 0; k0 < 512; k0 += 32){
        __syncthreads();
        gload_lds16(gA0 + k0, lA0);
        gload_lds16(gA1 + k0, lA1);
        gload_lds16(gB0 + k0, lB0);
        gload_lds16(gB1 + k0, lB1);
        __syncthreads();
        bf16x8 av[4], bv[4];
        #pragma unroll
        for (int mf=0;mf<4;mf++) av[mf] = *(const bf16x8*)&As[(wm*64 + mf*16 + li)*32 + lg*8];
        #pragma unroll
        for (int nf=0;nf<4;nf++) bv[nf] = *(const bf16x8*)&Bs[(wn*64 + nf*16 + li)*32 + lg*8];
        #pragma unroll
        for (int mf=0;mf<4;mf++)
            #pragma unroll
            for (int nf=0;nf<4;nf++)
                acc[mf][nf] = __builtin_amdgcn_mfma_f32_16x16x32_bf16(av[mf], bv[nf], acc[mf][nf], 0, 0, 0);
    }

    #pragma unroll
    for (int mf=0;mf<4;mf++)
        #pragma unroll
        for (int reg=0;reg<4;reg++){
            const int rr = mt*128 + wm*64 + mf*16 + lg*4 + reg;
            if (rr < TOK){
                #pragma unroll
                for (int nf=0;nf<4;nf++){
                    const int c = nt*128 + wn*64 + nf*16 + li;
                    fuse[(size_t)rr*512 + c] = acc[mf][nf][reg] + b_proj[c];
                }
            }
        }
}

// ---------------- residual + LayerNorm (with (b,j,n)->(b,n,j) permute) ----------------
__global__ __launch_bounds__(256) void k_ln(
    const float* __restrict__ x, const float* __restrict__ fuse, float* __restrict__ out)
{
    const int w = threadIdx.x >> 6, lane = threadIdx.x & 63;
    const int o = blockIdx.x*4 + w;
    const unsigned b_  = (unsigned)o / 4131u;
    const unsigned rem = (unsigned)o % 4131u;
    const unsigned n = rem / 17u, j = rem % 17u;
    const unsigned t = (b_*17u + j)*243u + n;
    const float* fr = fuse + (size_t)t*512 + lane*8;
    const float* xr = x    + (size_t)o*512 + lane*8;
    f32x4 f0 = *(const f32x4*)fr, f1 = *(const f32x4*)(fr+4);
    f32x4 x0 = *(const f32x4*)xr, x1 = *(const f32x4*)(xr+4);
    float y[8];
    #pragma unroll
    for (int e=0;e<4;e++){ y[e] = x0[e]+f0[e]; y[e+4] = x1[e]+f1[e]; }
    float s1=0.f, s2=0.f;
    #pragma unroll
    for (int e=0;e<8;e++){ s1 += y[e]; s2 += y[e]*y[e]; }
    #pragma unroll
    for (int m=1;m<64;m<<=1){ s1 += __shfl_xor(s1,m); s2 += __shfl_xor(s2,m); }
    const float mu  = s1 * (1.f/512.f);
    const float var = s2 * (1.f/512.f) - mu*mu;
    const float rstd = rsqrtf(var + 1e-5f);
    float* orow = out + (size_t)o*512 + lane*8;
    f32x4 o0, o1;
    #pragma unroll
    for (int e=0;e<4;e++){ o0[e] = (y[e]-mu)*rstd; o1[e] = (y[e+4]-mu)*rstd; }
    *(f32x4*)orow = o0; *(f32x4*)(orow+4) = o1;
}

extern "C" void kernel_launch(void* const* d_in, const int* in_sizes, int n_in,
                              void* d_out, int out_size, void* d_ws, size_t ws_size,
                              hipStream_t stream)
{
    const float* x      = (const float*)d_in[0];
    const float* W_qkv  = (const float*)d_in[1];
    const float* b_qkv  = (const float*)d_in[2];
    const float* W_q    = (const float*)d_in[3];
    const float* b_q    = (const float*)d_in[4];
    const float* W_kv   = (const float*)d_in[5];
    const float* b_kv   = (const float*)d_in[6];
    const float* W_proj = (const float*)d_in[7];
    const float* b_proj = (const float*)d_in[8];

    // workspace layout (peak ~175 MB):
    //   [0, 33972224)              xbf  bf16 [33048+pad][512]
    //   [33972224, 137306112)      ws3: Q [1088][243][64], K same, VT [1088][64][256]
    //   [137306112, 171278336)     attn bf16 [33048+pad][512]
    //   [171278336, 174424064)     WcatT bf16 [3072][512]
    //   [174424064, 174948352)     WprojT bf16 [512][512]
    //   fuse fp32 aliases ws3 (dead after attn phase 1)
    char* ws = (char*)d_ws;
    u16*   xbf    = (u16*)(ws);
    u16*   ws3    = (u16*)(ws + 33972224u);
    u16*   attn   = (u16*)(ws + 137306112u);
    u16*   WcatT  = (u16*)(ws + 171278336u);
    u16*   WprojT = (u16*)(ws + 174424064u);
    float* fuse   = (float*)(ws + 33972224u);
    float* out    = (float*)d_out;

    k_cvt_xbf  <<<8262, 256, 0, stream>>>(x, xbf);
    k_cvt_wcat <<<768,  256, 0, stream>>>(W_qkv, W_q, W_kv, WcatT);
    k_cvt_wproj<<<128,  256, 0, stream>>>(W_proj, WprojT);

    k_gemm_in<<<3108, 256, 0, stream>>>(xbf, WcatT, b_qkv, b_q, b_kv, ws3, 0);
    k_attn<<<2176, 256, 0, stream>>>(ws3, attn, 0);

    k_gemm_in<<<3108, 256, 0, stream>>>(xbf, WcatT, b_qkv, b_q, b_kv, ws3, 1536);
    k_attn<<<2176, 256, 0, stream>>>(ws3, attn, 1);

    k_gemm_proj<<<1036, 256, 0, stream>>>(attn, WprojT, b_proj, fuse);

    k_ln<<<8262, 256, 0, stream>>>(x, fuse, out);
}

// Round 9
// 476.133 us; speedup vs baseline: 1.2501x; 1.0002x over previous
//
#include <hip/hip_runtime.h>

typedef unsigned short u16;
typedef unsigned int u32;
typedef __attribute__((ext_vector_type(8))) short bf16x8;
typedef __attribute__((ext_vector_type(8))) u16  u16x8;
typedef __attribute__((ext_vector_type(4))) float f32x4;

#define TOK   33048      // B*J*N = 8*17*243
#define NSEQ  243
#define TE    16920576u  // elems per blocked Q/K tensor: 1088*243*64
#define GSTR  15552      // 243*64
#define VTP   256        // padded n-stride of V^T

__device__ __forceinline__ float bf2f(u16 u){
    union { unsigned int i; float f; } v; v.i = ((unsigned int)u) << 16; return v.f;
}
__device__ __forceinline__ u16 f2bf(float f){
    union { float f; unsigned int i; } v; v.f = f;
    unsigned int r = v.i + 0x7fffu + ((v.i >> 16) & 1u);
    return (u16)(r >> 16);
}

__device__ __forceinline__ void gload_lds16(const void* g, void* l){
    __builtin_amdgcn_global_load_lds(
        (const __attribute__((address_space(1))) unsigned int*)g,
        (__attribute__((address_space(3))) unsigned int*)l, 16, 0, 0);
}

// ---------------- x -> token-major bf16 ----------------
__global__ __launch_bounds__(256) void k_cvt_xbf(const float* __restrict__ x, u16* __restrict__ xbf){
    int idx = blockIdx.x*256 + threadIdx.x;
    int t  = idx >> 6;
    int c8 = (idx & 63) << 3;
    unsigned b   = (unsigned)t / 4131u;
    unsigned rem = (unsigned)t % 4131u;
    unsigned j = rem / 243u, n = rem % 243u;
    const float* src = x + ((size_t)(b*243u + n)*17u + j)*512u + c8;
    f32x4 a = *(const f32x4*)src;
    f32x4 c = *(const f32x4*)(src+4);
    u16x8 o;
    #pragma unroll
    for (int e=0;e<4;e++){ o[e]=f2bf(a[e]); o[e+4]=f2bf(c[e]); }
    *(u16x8*)(xbf + (size_t)t*512 + c8) = o;
}

// ---------------- weight conversions ----------------
__global__ __launch_bounds__(256) void k_cvt_wcat(const float* __restrict__ Wqkv,
                                                  const float* __restrict__ Wq,
                                                  const float* __restrict__ Wkv,
                                                  u16* __restrict__ WcatT){
    int idx = blockIdx.x*256 + threadIdx.x;
    int k  = idx / 384;
    int c0 = (idx % 384) * 8;
    const float* src;
    if (c0 < 1536)      src = Wqkv + (size_t)k*1536 + c0;
    else if (c0 < 2048) src = Wq   + (size_t)k*512  + (c0 - 1536);
    else                src = Wkv  + (size_t)k*1024 + (c0 - 2048);
    f32x4 a = *(const f32x4*)src;
    f32x4 b = *(const f32x4*)(src+4);
    #pragma unroll
    for (int e=0;e<4;e++){
        WcatT[(size_t)(c0+e)*512 + k]   = f2bf(a[e]);
        WcatT[(size_t)(c0+4+e)*512 + k] = f2bf(b[e]);
    }
}

__global__ __launch_bounds__(256) void k_cvt_wproj(const float* __restrict__ Wp, u16* __restrict__ WpT){
    int idx = blockIdx.x*256 + threadIdx.x;
    int k  = idx / 64;
    int c0 = (idx % 64) * 8;
    f32x4 a = *(const f32x4*)(Wp + (size_t)k*512 + c0);
    f32x4 b = *(const f32x4*)(Wp + (size_t)k*512 + c0 + 4);
    #pragma unroll
    for (int e=0;e<4;e++){
        WpT[(size_t)(c0+e)*512 + k]   = f2bf(a[e]);
        WpT[(size_t)(c0+4+e)*512 + k] = f2bf(b[e]);
    }
}

// ---------------- input GEMM  M=33048 x N=1536(half) x K=512 ----------------
// writes blocked Q=[g][243][64] @0, K @TE, and V TRANSPOSED VT=[g][64][VTP] @2*TE
__global__ __launch_bounds__(256) void k_gemm_in(
    const u16* __restrict__ xbf, const u16* __restrict__ WcatT,
    const float* __restrict__ b_qkv, const float* __restrict__ b_q,
    const float* __restrict__ b_kv, u16* __restrict__ ws3, int c_off)
{
    __shared__ __align__(16) u16 smem[8192];
    u16* As = smem;
    u16* Bs = smem + 4096;

    // bijective XCD swizzle over 3108 blocks (q=388, r=4)
    const int orig = blockIdx.x;
    const int xcd  = orig & 7;
    const int wg   = (xcd < 4 ? xcd*389 : 4*389 + (xcd-4)*388) + (orig >> 3);
    const int nt = wg % 12, mt = wg / 12;

    const int tid = threadIdx.x;
    const int w = tid >> 6, lane = tid & 63;
    const int wm = w >> 1, wn = w & 1;
    const int lg = lane >> 4, li = lane & 15;

    const int srow = w*16 + (lane >> 2);
    const int scol = (lane & 3) * 8;
    const u16* gA0 = xbf   + (size_t)(mt*128 + srow)*512 + scol;
    const u16* gA1 = gA0 + (size_t)64*512;
    const u16* gB0 = WcatT + (size_t)(c_off + nt*128 + srow)*512 + scol;
    const u16* gB1 = gB0 + (size_t)64*512;
    u16* lA0 = As + w*512;           u16* lA1 = As + 2048 + w*512;
    u16* lB0 = Bs + w*512;           u16* lB1 = Bs + 2048 + w*512;

    f32x4 acc[4][4];
    #pragma unroll
    for (int i=0;i<4;i++)
        #pragma unroll
        for (int jj=0;jj<4;jj++){ acc[i][jj][0]=0.f; acc[i][jj][1]=0.f; acc[i][jj][2]=0.f; acc[i][jj][3]=0.f; }

    for (int k0 = 0; k0 < 512; k0 += 32){
        __syncthreads();
        gload_lds16(gA0 + k0, lA0);
        gload_lds16(gA1 + k0, lA1);
        gload_lds16(gB0 + k0, lB0);
        gload_lds16(gB1 + k0, lB1);
        __syncthreads();
        bf16x8 av[4], bv[4];
        #pragma unroll
        for (int mf=0;mf<4;mf++) av[mf] = *(const bf16x8*)&As[(wm*64 + mf*16 + li)*32 + lg*8];
        #pragma unroll
        for (int nf=0;nf<4;nf++) bv[nf] = *(const bf16x8*)&Bs[(wn*64 + nf*16 + li)*32 + lg*8];
        #pragma unroll
        for (int mf=0;mf<4;mf++)
            #pragma unroll
            for (int nf=0;nf<4;nf++)
                acc[mf][nf] = __builtin_amdgcn_mfma_f32_16x16x32_bf16(av[mf], bv[nf], acc[mf][nf], 0, 0, 0);
    }

    float bias[4];
    #pragma unroll
    for (int nf=0;nf<4;nf++){
        const int c = c_off + nt*128 + wn*64 + nf*16 + li;
        bias[nf] = (c < 1536) ? b_qkv[c] : (c < 2048 ? b_q[c-1536] : b_kv[c-2048]);
    }

    // epilogue: per-wave 16x72 LDS tile -> blocked stores
    u16* L = smem + w*1152;
    const int colbase = nt*128 + wn*64;        // within this half; multiple of 64
    const int slot = colbase >> 9;             // 0=Q,1=K,2=V
    const int hh   = (colbase >> 6) & 7;
    const int rloc = lane & 15;
    const int cchunk = lane >> 4;
    const int dd = (colbase + cchunk*8) & 63;
    u16* tbase = ws3 + (size_t)slot * TE;
    u16* vt    = ws3 + (size_t)2 * TE;

    #pragma unroll
    for (int mf=0;mf<4;mf++){
        __syncthreads();
        #pragma unroll
        for (int nf=0;nf<4;nf++)
            #pragma unroll
            for (int reg=0;reg<4;reg++)
                L[(lg*4+reg)*72 + nf*16 + li] = f2bf(acc[mf][nf][reg] + bias[nf]);
        __syncthreads();
        const int rr_base = mt*128 + wm*64 + mf*16;
        if (slot < 2){
            const int rr = rr_base + rloc;
            if (rr < TOK){
                u16x8 v0 = *(const u16x8*)&L[rloc*72 + cchunk*8];
                u16x8 v1 = *(const u16x8*)&L[rloc*72 + 32 + cchunk*8];
                const unsigned bj = (unsigned)rr / 243u;
                const unsigned n  = (unsigned)rr % 243u;
                u16* dst = tbase + ((size_t)(bj*8u + hh)*243u + n)*64u + dd;
                *(u16x8*)dst      = v0;
                *(u16x8*)(dst+32) = v1;
            }
        } else {
            // V^T: lane owns column d = lane; read 16 u16 down the column
            u16 colv[16];
            #pragma unroll
            for (int r=0;r<16;r++) colv[r] = L[r*72 + lane];
            if (rr_base < TOK){
                const unsigned bj0 = (unsigned)rr_base / 243u;
                const unsigned n0  = (unsigned)rr_base % 243u;
                if (n0 <= 227 && rr_base + 15 < TOK){
                    u16x8 vlo, vhi;
                    #pragma unroll
                    for (int e=0;e<8;e++){ vlo[e]=colv[e]; vhi[e]=colv[e+8]; }
                    u16* dst = vt + ((size_t)(bj0*8u + hh)*64u + lane)*VTP + n0;
                    *(u16x8*)dst     = vlo;
                    *(u16x8*)(dst+8) = vhi;
                } else {
                    for (int r=0;r<16;r++){
                        const int rr = rr_base + r;
                        if (rr < TOK){
                            const unsigned bjr = (unsigned)rr / 243u;
                            const unsigned nr  = (unsigned)rr % 243u;
                            vt[((size_t)(bjr*8u + hh)*64u + lane)*VTP + nr] = colv[r];
                        }
                    }
                }
            }
        }
    }
}

// ---------------- fused attention: no LDS/barriers; 2 q-tiles per wave ----------------
// grid 2176 = 1088 g x 2 halves; block covers 128 q-rows (4 waves x 2 tiles of 16)
__constant__ int g_child[17][3] = {
  {1,4,7},{2,-1,-1},{3,-1,-1},{3,-1,-1},{5,-1,-1},{6,-1,-1},{6,-1,-1},{8,-1,-1},
  {9,11,14},{10,-1,-1},{10,-1,-1},{12,-1,-1},{13,-1,-1},{13,-1,-1},{15,-1,-1},
  {16,-1,-1},{16,-1,-1}};
__constant__ float g_cw[17] = {0.33333333f,1,1,1,1,1,1,1,0.33333333f,1,1,1,1,1,1,1,1};

__global__ __launch_bounds__(256, 2) void k_attn(const u16* __restrict__ ws3, u16* __restrict__ attn, int phase)
{
    // XCD-grouping swizzle: both halves of a g land on one XCD
    const int orig = blockIdx.x;               // 2176
    const int xcd  = orig & 7;
    const int l    = orig >> 3;                // 0..271
    const int p2   = l & 1;
    const int g    = (l >> 1)*8 + xcd;
    const int bj = g >> 3, h = g & 7;
    const int b_ = bj / 17, j_ = bj % 17;

    const int tid = threadIdx.x, lane = tid & 63, w = tid >> 6;
    const int lg = lane >> 4, li = lane & 15;

    const u16* Qb = ws3;
    const u16* Kb = ws3 + (size_t)TE;
    const u16* VT = ws3 + (size_t)2*TE;

    const float scale = (phase == 0) ? 0.125f : 0.125f * g_cw[j_];

    const int qrowA = p2*128 + w*16;
    const int qrowB = qrowA + 64;

    bf16x8 qA0 = {0,0,0,0,0,0,0,0}, qA1 = qA0, qB0 = qA0, qB1 = qA0;
    {
        const int qrA = qrowA + li;
        const u16* qp = Qb + (size_t)g*GSTR + (size_t)qrA*64;
        qA0 = *(const bf16x8*)(qp + lg*8);
        qA1 = *(const bf16x8*)(qp + 32 + lg*8);
        const int qrB = qrowB + li;
        if (qrB < NSEQ){
            const u16* qp2 = Qb + (size_t)g*GSTR + (size_t)qrB*64;
            qB0 = *(const bf16x8*)(qp2 + lg*8);
            qB1 = *(const bf16x8*)(qp2 + 32 + lg*8);
        }
    }

    // child K/V base offsets (wave-uniform)
    size_t kgb[3]; int nch = 0;
    if (phase == 0){
        kgb[0] = (size_t)g*GSTR; nch = 1;
    } else {
        #pragma unroll
        for (int ci=0; ci<3; ci++){
            const int cj = g_child[j_][ci];
            if (cj >= 0) kgb[nch++] = (size_t)((b_*17+cj)*8 + h)*GSTR;
        }
    }

    // S^T: lane li owns q-row li of each tile; fused QK -> mask -> exp -> sum -> pack
    u32 uloA[16], uhiA[16], uloB[16], uhiB[16];
    float sumA = 0.f, sumB = 0.f;
    #pragma unroll
    for (int nt2=0; nt2<16; nt2++){
        f32x4 sA; sA[0]=0.f; sA[1]=0.f; sA[2]=0.f; sA[3]=0.f;
        f32x4 sB = sA;
        const size_t krow = (size_t)(nt2*16+li)*64;
        if (nch == 1){
            const u16* kp = Kb + kgb[0] + krow;
            const bf16x8 kb0 = *(const bf16x8*)(kp + lg*8);
            const bf16x8 kb1 = *(const bf16x8*)(kp + 32 + lg*8);
            sA = __builtin_amdgcn_mfma_f32_16x16x32_bf16(kb0, qA0, sA, 0,0,0);
            sA = __builtin_amdgcn_mfma_f32_16x16x32_bf16(kb1, qA1, sA, 0,0,0);
            sB = __builtin_amdgcn_mfma_f32_16x16x32_bf16(kb0, qB0, sB, 0,0,0);
            sB = __builtin_amdgcn_mfma_f32_16x16x32_bf16(kb1, qB1, sB, 0,0,0);
        } else {
            #pragma unroll
            for (int c=0;c<3;c++){
                const u16* kp = Kb + kgb[c] + krow;
                const bf16x8 kb0 = *(const bf16x8*)(kp + lg*8);
                const bf16x8 kb1 = *(const bf16x8*)(kp + 32 + lg*8);
                sA = __builtin_amdgcn_mfma_f32_16x16x32_bf16(kb0, qA0, sA, 0,0,0);
                sA = __builtin_amdgcn_mfma_f32_16x16x32_bf16(kb1, qA1, sA, 0,0,0);
                sB = __builtin_amdgcn_mfma_f32_16x16x32_bf16(kb0, qB0, sB, 0,0,0);
                sB = __builtin_amdgcn_mfma_f32_16x16x32_bf16(kb1, qB1, sB, 0,0,0);
            }
        }
        if (nt2 == 15){
            sA[3] = -1e30f; sB[3] = -1e30f;
            if (lg){ sA[0]=-1e30f; sA[1]=-1e30f; sA[2]=-1e30f;
                     sB[0]=-1e30f; sB[1]=-1e30f; sB[2]=-1e30f; }
        }
        const float a0 = __expf(scale*sA[0]);
        const float a1 = __expf(scale*sA[1]);
        const float a2 = __expf(scale*sA[2]);
        const float a3 = __expf(scale*sA[3]);
        sumA += (a0+a1)+(a2+a3);
        uloA[nt2] = (u32)f2bf(a0) | ((u32)f2bf(a1) << 16);
        uhiA[nt2] = (u32)f2bf(a2) | ((u32)f2bf(a3) << 16);
        const float b0 = __expf(scale*sB[0]);
        const float b1 = __expf(scale*sB[1]);
        const float b2 = __expf(scale*sB[2]);
        const float b3 = __expf(scale*sB[3]);
        sumB += (b0+b1)+(b2+b3);
        uloB[nt2] = (u32)f2bf(b0) | ((u32)f2bf(b1) << 16);
        uhiB[nt2] = (u32)f2bf(b2) | ((u32)f2bf(b3) << 16);
    }
    sumA += __shfl_xor(sumA,16); sumA += __shfl_xor(sumA,32);
    sumB += __shfl_xor(sumB,16); sumB += __shfl_xor(sumB,32);
    const float invA = 1.f/sumA;
    const float invB = 1.f/sumB;

    // redistribute to PV A-fragments: pa[kt] elem e = P[q=li][k=kt*32+lg*8+e]
    const int laneA = li + 32*(lg & 1);
    const int laneB = laneA + 16;
    const bool sel = (lg >> 1) != 0;
    bf16x8 paA[8], paB[8];
    #pragma unroll
    for (int kt=0; kt<8; kt++){
        u32 a0 = __shfl((int)uloA[2*kt],   laneA), a1 = __shfl((int)uloA[2*kt+1], laneA);
        u32 b0 = __shfl((int)uhiA[2*kt],   laneA), b1 = __shfl((int)uhiA[2*kt+1], laneA);
        u32 c0 = __shfl((int)uloA[2*kt],   laneB), c1 = __shfl((int)uloA[2*kt+1], laneB);
        u32 d0 = __shfl((int)uhiA[2*kt],   laneB), d1 = __shfl((int)uhiA[2*kt+1], laneB);
        union { u32 u[4]; bf16x8 v; } pk;
        pk.u[0] = sel ? a1 : a0;
        pk.u[1] = sel ? b1 : b0;
        pk.u[2] = sel ? c1 : c0;
        pk.u[3] = sel ? d1 : d0;
        paA[kt] = pk.v;
    }
    #pragma unroll
    for (int kt=0; kt<8; kt++){
        u32 a0 = __shfl((int)uloB[2*kt],   laneA), a1 = __shfl((int)uloB[2*kt+1], laneA);
        u32 b0 = __shfl((int)uhiB[2*kt],   laneA), b1 = __shfl((int)uhiB[2*kt+1], laneA);
        u32 c0 = __shfl((int)uloB[2*kt],   laneB), c1 = __shfl((int)uloB[2*kt+1], laneB);
        u32 d0 = __shfl((int)uhiB[2*kt],   laneB), d1 = __shfl((int)uhiB[2*kt+1], laneB);
        union { u32 u[4]; bf16x8 v; } pk;
        pk.u[0] = sel ? a1 : a0;
        pk.u[1] = sel ? b1 : b0;
        pk.u[2] = sel ? c1 : c0;
        pk.u[3] = sel ? d1 : d0;
        paB[kt] = pk.v;
    }
    const float cwo = (phase == 0) ? 1.f : g_cw[j_];
    float invrA[4], invrB[4];
    #pragma unroll
    for (int r=0;r<4;r++){
        invrA[r] = __shfl(invA, lg*4+r) * cwo;
        invrB[r] = __shfl(invB, lg*4+r) * cwo;
    }

    // O = P V from global V^T (phase 1: O = sum over children); vb shared by both tiles
    #pragma unroll
    for (int dn=0;dn<4;dn++){
        f32x4 oA; oA[0]=0.f; oA[1]=0.f; oA[2]=0.f; oA[3]=0.f;
        f32x4 oB = oA;
        const size_t vrow = ((size_t)(dn*16 + li))*VTP;
        if (nch == 1){
            const u16* vbase = VT + kgb[0]/GSTR*((size_t)64*VTP) + vrow;
            bf16x8 vb[8];
            #pragma unroll
            for (int kt=0;kt<8;kt++) vb[kt] = *(const bf16x8*)(vbase + kt*32 + lg*8);
            #pragma unroll
            for (int kt=0;kt<8;kt++){
                oA = __builtin_amdgcn_mfma_f32_16x16x32_bf16(paA[kt], vb[kt], oA, 0,0,0);
                oB = __builtin_amdgcn_mfma_f32_16x16x32_bf16(paB[kt], vb[kt], oB, 0,0,0);
            }
        } else {
            #pragma unroll
            for (int c=0;c<3;c++){
                const u16* vbase = VT + kgb[c]/GSTR*((size_t)64*VTP) + vrow;
                bf16x8 vb[8];
                #pragma unroll
                for (int kt=0;kt<8;kt++) vb[kt] = *(const bf16x8*)(vbase + kt*32 + lg*8);
                #pragma unroll
                for (int kt=0;kt<8;kt++){
                    oA = __builtin_amdgcn_mfma_f32_16x16x32_bf16(paA[kt], vb[kt], oA, 0,0,0);
                    oB = __builtin_amdgcn_mfma_f32_16x16x32_bf16(paB[kt], vb[kt], oB, 0,0,0);
                }
            }
        }
        #pragma unroll
        for (int r=0;r<4;r++){
            const int qrow = qrowA + lg*4 + r;
            const size_t off = ((size_t)bj*243 + qrow)*512 + h*64 + dn*16 + li;
            float val = oA[r] * invrA[r];
            if (phase == 1) val += bf2f(attn[off]);
            attn[off] = f2bf(val);
        }
        #pragma unroll
        for (int r=0;r<4;r++){
            const int qrow = qrowB + lg*4 + r;
            if (qrow < NSEQ){
                const size_t off = ((size_t)bj*243 + qrow)*512 + h*64 + dn*16 + li;
                float val = oB[r] * invrB[r];
                if (phase == 1) val += bf2f(attn[off]);
                attn[off] = f2bf(val);
            }
        }
    }
}

// ---------------- projection GEMM  M=33048 x N=512 x K=512 -> fp32 fuse ----------------
__global__ __launch_bounds__(256) void k_gemm_proj(
    const u16* __restrict__ attnb, const u16* __restrict__ WprojT,
    const float* __restrict__ b_proj, float* __restrict__ fuse)
{
    __shared__ __align__(16) u16 smem[8192];
    u16* As = smem;
    u16* Bs = smem + 4096;

    const int orig = blockIdx.x;
    const int xcd  = orig & 7;
    const int wg   = (xcd < 4 ? xcd*130 : 4*130 + (xcd-4)*129) + (orig >> 3);
    const int nt = wg & 3, mt = wg >> 2;

    const int tid = threadIdx.x;
    const int w = tid >> 6, lane = tid & 63;
    const int wm = w >> 1, wn = w & 1;
    const int lg = lane >> 4, li = lane & 15;

    const int srow = w*16 + (lane >> 2);
    const int scol = (lane & 3) * 8;
    const u16* gA0 = attnb  + (size_t)(mt*128 + srow)*512 + scol;
    const u16* gA1 = gA0 + (size_t)64*512;
    const u16* gB0 = WprojT + (size_t)(nt*128 + srow)*512 + scol;
    const u16* gB1 = gB0 + (size_t)64*512;
    u16* lA0 = As + w*512;           u16* lA1 = As + 2048 + w*512;
    u16* lB0 = Bs + w*512;           u16* lB1 = Bs + 2048 + w*512;

    f32x4 acc[4][4];
    #pragma unroll
    for (int i=0;i<4;i++)
        #pragma unroll
        for (int jj=0;jj<4;jj++){ acc[i][jj][0]=0.f; acc[i][jj][1]=0.f; acc[i][jj][2]=0.f; acc[i][jj][3]=0.f; }

    for (int k0 = 0; k0 < 512; k0 += 32){
        __syncthreads();
        gload_lds16(gA0 + k0, lA0);
        gload_lds16(gA1 + k0, lA1);
        gload_lds16(gB0 + k0, lB0);
        gload_lds16(gB1 + k0, lB1);
        __syncthreads();
        bf16x8 av[4], bv[4];
        #pragma unroll
        for (int mf=0;mf<4;mf++) av[mf] = *(const bf16x8*)&As[(wm*64 + mf*16 + li)*32 + lg*8];
        #pragma unroll
        for (int nf=0;nf<4;nf++) bv[nf] = *(const bf16x8*)&Bs[(wn*64 + nf*16 + li)*32 + lg*8];
        #pragma unroll
        for (int mf=0;mf<4;mf++)
            #pragma unroll
            for (int nf=0;nf<4;nf++)
                acc[mf][nf] = __builtin_amdgcn_mfma_f32_16x16x32_bf16(av[mf], bv[nf], acc[mf][nf], 0, 0, 0);
    }

    #pragma unroll
    for (int mf=0;mf<4;mf++)
        #pragma unroll
        for (int reg=0;reg<4;reg++){
            const int rr = mt*128 + wm*64 + mf*16 + lg*4 + reg;
            if (rr < TOK){
                #pragma unroll
                for (int nf=0;nf<4;nf++){
                    const int c = nt*128 + wn*64 + nf*16 + li;
                    fuse[(size_t)rr*512 + c] = acc[mf][nf][reg] + b_proj[c];
                }
            }
        }
}

// ---------------- residual + LayerNorm (with (b,j,n)->(b,n,j) permute) ----------------
__global__ __launch_bounds__(256) void k_ln(
    const float* __restrict__ x, const float* __restrict__ fuse, float* __restrict__ out)
{
    const int w = threadIdx.x >> 6, lane = threadIdx.x & 63;
    const int o = blockIdx.x*4 + w;
    const unsigned b_  = (unsigned)o / 4131u;
    const unsigned rem = (unsigned)o % 4131u;
    const unsigned n = rem / 17u, j = rem % 17u;
    const unsigned t = (b_*17u + j)*243u + n;
    const float* fr = fuse + (size_t)t*512 + lane*8;
    const float* xr = x    + (size_t)o*512 + lane*8;
    f32x4 f0 = *(const f32x4*)fr, f1 = *(const f32x4*)(fr+4);
    f32x4 x0 = *(const f32x4*)xr, x1 = *(const f32x4*)(xr+4);
    float y[8];
    #pragma unroll
    for (int e=0;e<4;e++){ y[e] = x0[e]+f0[e]; y[e+4] = x1[e]+f1[e]; }
    float s1=0.f, s2=0.f;
    #pragma unroll
    for (int e=0;e<8;e++){ s1 += y[e]; s2 += y[e]*y[e]; }
    #pragma unroll
    for (int m=1;m<64;m<<=1){ s1 += __shfl_xor(s1,m); s2 += __shfl_xor(s2,m); }
    const float mu  = s1 * (1.f/512.f);
    const float var = s2 * (1.f/512.f) - mu*mu;
    const float rstd = rsqrtf(var + 1e-5f);
    float* orow = out + (size_t)o*512 + lane*8;
    f32x4 o0, o1;
    #pragma unroll
    for (int e=0;e<4;e++){ o0[e] = (y[e]-mu)*rstd; o1[e] = (y[e+4]-mu)*rstd; }
    *(f32x4*)orow = o0; *(f32x4*)(orow+4) = o1;
}

extern "C" void kernel_launch(void* const* d_in, const int* in_sizes, int n_in,
                              void* d_out, int out_size, void* d_ws, size_t ws_size,
                              hipStream_t stream)
{
    const float* x      = (const float*)d_in[0];
    const float* W_qkv  = (const float*)d_in[1];
    const float* b_qkv  = (const float*)d_in[2];
    const float* W_q    = (const float*)d_in[3];
    const float* b_q    = (const float*)d_in[4];
    const float* W_kv   = (const float*)d_in[5];
    const float* b_kv   = (const float*)d_in[6];
    const float* W_proj = (const float*)d_in[7];
    const float* b_proj = (const float*)d_in[8];

    // workspace layout (peak ~175 MB):
    //   [0, 33972224)              xbf  bf16 [33048+pad][512]
    //   [33972224, 137306112)      ws3: Q [1088][243][64], K same, VT [1088][64][256]
    //   [137306112, 171278336)     attn bf16 [33048+pad][512]
    //   [171278336, 174424064)     WcatT bf16 [3072][512]
    //   [174424064, 174948352)     WprojT bf16 [512][512]
    //   fuse fp32 aliases ws3 (dead after attn phase 1)
    char* ws = (char*)d_ws;
    u16*   xbf    = (u16*)(ws);
    u16*   ws3    = (u16*)(ws + 33972224u);
    u16*   attn   = (u16*)(ws + 137306112u);
    u16*   WcatT  = (u16*)(ws + 171278336u);
    u16*   WprojT = (u16*)(ws + 174424064u);
    float* fuse   = (float*)(ws + 33972224u);
    float* out    = (float*)d_out;

    k_cvt_xbf  <<<8262, 256, 0, stream>>>(x, xbf);
    k_cvt_wcat <<<768,  256, 0, stream>>>(W_qkv, W_q, W_kv, WcatT);
    k_cvt_wproj<<<128,  256, 0, stream>>>(W_proj, WprojT);

    k_gemm_in<<<3108, 256, 0, stream>>>(xbf, WcatT, b_qkv, b_q, b_kv, ws3, 0);
    k_attn<<<2176, 256, 0, stream>>>(ws3, attn, 0);

    k_gemm_in<<<3108, 256, 0, stream>>>(xbf, WcatT, b_qkv, b_q, b_kv, ws3, 1536);
    k_attn<<<2176, 256, 0, stream>>>(ws3, attn, 1);

    k_gemm_proj<<<1036, 256, 0, stream>>>(attn, WprojT, b_proj, fuse);

    k_ln<<<8262, 256, 0, stream>>>(x, fuse, out);
}